// Round 9
// baseline (105.613 us; speedup 1.0000x reference)
//
#include <hip/hip_runtime.h>

#define NN   67   // N_OUT + N_HID
#define NOUT 3
#define NIN  4
#define PKW  16                      // floats per neuron in packed blob (64B aligned)
#define PK_FLOATS (NN * PKW)
#define PK_BYTES  (PK_FLOATS * 4)
#define C2   2.885390081777927f      // 2*log2(e)

#if __has_builtin(__builtin_amdgcn_exp2f)
  #define EXP2F __builtin_amdgcn_exp2f
#else
  #define EXP2F exp2f
#endif
#if __has_builtin(__builtin_amdgcn_rcpf)
  #define RCPF __builtin_amdgcn_rcpf
#else
  #define RCPF(x) (1.0f/(x))
#endif

// tanh(y) with arg = 2*log2(e)*y pre-applied: tanh = 1 - 2*rcp(exp2(arg)+1)
__device__ __forceinline__ float tanh_sc(float arg) {
    float e = EXP2F(arg);
    float r = RCPF(e + 1.0f);
    return __builtin_fmaf(-2.0f, r, 1.0f);
}

// Pack per-neuron data: {Win[0..3][j], resp2, bias2, Wrec[j][0..2], pad×7}
// resp2 = hasin*resp*C2, bias2 = hasin*bias*C2  (hasin ∈ {0,1}: h*tanh(y)=tanh(h*y))
__global__ void pack_kernel(const float* __restrict__ Win,
                            const float* __restrict__ Wrec,
                            const float* __restrict__ bias,
                            const float* __restrict__ resp,
                            const float* __restrict__ hasin,
                            float* __restrict__ pk)
{
    int j = threadIdx.x;
    if (j < NN) {
        float h = hasin[j];
        float* p = pk + j * PKW;
        p[0] = Win[0*NN + j]; p[1] = Win[1*NN + j];
        p[2] = Win[2*NN + j]; p[3] = Win[3*NN + j];
        p[4] = resp[j] * h * C2;
        p[5] = bias[j] * h * C2;
        p[6] = Wrec[j*NN + 0]; p[7] = Wrec[j*NN + 1]; p[8] = Wrec[j*NN + 2];
        p[9]=p[10]=p[11]=p[12]=p[13]=p[14]=p[15] = 0.f;
    }
}

template<int P>
__global__ __launch_bounds__(256)
void rnn_fused(const float* __restrict__ inputs,
               const float* __restrict__ pk,
               const float* __restrict__ Wrec,
               const int*   __restrict__ np_ptr,
               float*       __restrict__ out,
               int total)
{
    // Stage packed weights into LDS (4.2 KB). Uniform-address ds_reads
    // broadcast conflict-free, return IN-ORDER (unlike s_load, which forces
    // lgkmcnt(0) full drains), and the free VGPR budget lets the compiler
    // pipeline reads across the unrolled iterations.
    __shared__ __align__(16) float spk[PK_FLOATS];
    {
        float4*       d = reinterpret_cast<float4*>(spk);
        const float4* s = reinterpret_cast<const float4*>(pk);
        #pragma unroll
        for (int t = 0; t < 2; ++t) {
            int i = threadIdx.x + t * 256;
            if (i < PK_FLOATS / 4) d[i] = s[i];
        }
    }
    __syncthreads();

    const int np   = np_ptr[0];                       // uniform
    const int base = blockIdx.x * (256 * P) + threadIdx.x;

    int    pix[P];
    float4 x[P];
#pragma unroll
    for (int p = 0; p < P; ++p) {                     // coalesced 16B loads
        pix[p] = base + p * 256;
        int idx = pix[p] < total ? pix[p] : total - 1;
        x[p] = reinterpret_cast<const float4*>(inputs)[idx];
    }

    float res[P][NOUT];

    if (np == 2) {
        // ---- HOT PATH: pass0 fused into final; a_j dies immediately ----
        float acc[P][NOUT];
#pragma unroll
        for (int p = 0; p < P; ++p)
#pragma unroll
            for (int c = 0; c < NOUT; ++c) {          // final-pass x@Win[:,c] term
                const float* q = &spk[c * PKW];
                float a = x[p].x * q[0];
                a = __builtin_fmaf(x[p].y, q[1], a);
                a = __builtin_fmaf(x[p].z, q[2], a);
                a = __builtin_fmaf(x[p].w, q[3], a);
                acc[p][c] = a;
            }
#pragma unroll
        for (int j = 0; j < NN; ++j) {
            const float* q = &spk[j * PKW];
            const float4 qa = *reinterpret_cast<const float4*>(q);     // w0..w3
            const float4 qb = *reinterpret_cast<const float4*>(q + 4); // r2,b2,wr0,wr1
            const float  wr2 = q[8];
#pragma unroll
            for (int p = 0; p < P; ++p) {
                float agg = x[p].x * qa.x;
                agg = __builtin_fmaf(x[p].y, qa.y, agg);
                agg = __builtin_fmaf(x[p].z, qa.z, agg);
                agg = __builtin_fmaf(x[p].w, qa.w, agg);
                float a = tanh_sc(__builtin_fmaf(qb.x, agg, qb.y));
                acc[p][0] = __builtin_fmaf(a, qb.z, acc[p][0]);
                acc[p][1] = __builtin_fmaf(a, qb.w, acc[p][1]);
                acc[p][2] = __builtin_fmaf(a, wr2,  acc[p][2]);
            }
        }
#pragma unroll
        for (int p = 0; p < P; ++p)
#pragma unroll
            for (int c = 0; c < NOUT; ++c) {
                const float* q = &spk[c * PKW];
                res[p][c] = tanh_sc(__builtin_fmaf(q[4], acc[p][c], q[5]));
            }
    } else if (np <= 0) {
#pragma unroll
        for (int p = 0; p < P; ++p)
#pragma unroll
            for (int c = 0; c < NOUT; ++c) res[p][c] = 0.f;
    } else if (np == 1) {
#pragma unroll
        for (int p = 0; p < P; ++p)
#pragma unroll
            for (int c = 0; c < NOUT; ++c) {
                const float* q = &spk[c * PKW];
                float agg = x[p].x * q[0];
                agg = __builtin_fmaf(x[p].y, q[1], agg);
                agg = __builtin_fmaf(x[p].z, q[2], agg);
                agg = __builtin_fmaf(x[p].w, q[3], agg);
                res[p][c] = tanh_sc(__builtin_fmaf(q[4], agg, q[5]));
            }
    } else {
        // ---- COLD general path (np >= 3): unroll-1 + runtime indexing so
        // its arrays live in scratch and don't inflate hot-path registers ----
#pragma unroll
        for (int p = 0; p < P; ++p) {
            float act[NN];
            #pragma unroll 1
            for (int j = 0; j < NN; ++j) {
                const float* q = &spk[j * PKW];
                float agg = x[p].x * q[0];
                agg = __builtin_fmaf(x[p].y, q[1], agg);
                agg = __builtin_fmaf(x[p].z, q[2], agg);
                agg = __builtin_fmaf(x[p].w, q[3], agg);
                act[j] = tanh_sc(__builtin_fmaf(q[4], agg, q[5]));
            }
            #pragma unroll 1
            for (int t = 1; t < np - 1; ++t) {
                float na[NN];
                #pragma unroll 1
                for (int j = 0; j < NN; ++j) {
                    const float* q = &spk[j * PKW];
                    float agg = x[p].x * q[0];
                    agg = __builtin_fmaf(x[p].y, q[1], agg);
                    agg = __builtin_fmaf(x[p].z, q[2], agg);
                    agg = __builtin_fmaf(x[p].w, q[3], agg);
                    #pragma unroll 1
                    for (int k = 0; k < NN; ++k)
                        agg = __builtin_fmaf(act[k], Wrec[k*NN + j], agg);
                    na[j] = tanh_sc(__builtin_fmaf(q[4], agg, q[5]));
                }
                #pragma unroll 1
                for (int j = 0; j < NN; ++j) act[j] = na[j];
            }
            #pragma unroll
            for (int c = 0; c < NOUT; ++c) {
                const float* q = &spk[c * PKW];
                float agg = x[p].x * q[0];
                agg = __builtin_fmaf(x[p].y, q[1], agg);
                agg = __builtin_fmaf(x[p].z, q[2], agg);
                agg = __builtin_fmaf(x[p].w, q[3], agg);
                #pragma unroll 1
                for (int k = 0; k < NN; ++k)
                    agg = __builtin_fmaf(act[k], Wrec[k*NN + c], agg);
                res[p][c] = tanh_sc(__builtin_fmaf(q[4], agg, q[5]));
            }
        }
    }

#pragma unroll
    for (int p = 0; p < P; ++p)
        if (pix[p] < total) {
            out[pix[p]*NOUT + 0] = res[p][0];
            out[pix[p]*NOUT + 1] = res[p][1];
            out[pix[p]*NOUT + 2] = res[p][2];
        }
}

// ---------- fallback (ws too small): self-contained, any np ----------
__global__ __launch_bounds__(256)
void rnn_general(const float* __restrict__ inputs,
                 const float* __restrict__ Win,
                 const float* __restrict__ Wrec,
                 const float* __restrict__ bias,
                 const float* __restrict__ resp,
                 const float* __restrict__ hasin,
                 const int*   __restrict__ np_ptr,
                 float*       __restrict__ out, int total)
{
    int pix = blockIdx.x * blockDim.x + threadIdx.x;
    if (pix >= total) return;
    const int np = np_ptr[0];
    const float4 x = reinterpret_cast<const float4*>(inputs)[pix];
    float act[NN];
    #pragma unroll 1
    for (int j = 0; j < NN; ++j) act[j] = 0.f;
    #pragma unroll 1
    for (int t = 0; t < np; ++t) {
        float na[NN];
        #pragma unroll 1
        for (int j = 0; j < NN; ++j) {
            float agg = x.x * Win[0*NN+j];
            agg = __builtin_fmaf(x.y, Win[1*NN+j], agg);
            agg = __builtin_fmaf(x.z, Win[2*NN+j], agg);
            agg = __builtin_fmaf(x.w, Win[3*NN+j], agg);
            #pragma unroll 1
            for (int k = 0; k < NN; ++k)
                agg = __builtin_fmaf(act[k], Wrec[k*NN + j], agg);
            na[j] = hasin[j] * tanh_sc(C2 * __builtin_fmaf(resp[j], agg, bias[j]));
        }
        #pragma unroll 1
        for (int j = 0; j < NN; ++j) act[j] = na[j];
    }
    out[pix*NOUT+0] = act[0]; out[pix*NOUT+1] = act[1]; out[pix*NOUT+2] = act[2];
}

extern "C" void kernel_launch(void* const* d_in, const int* in_sizes, int n_in,
                              void* d_out, int out_size, void* d_ws, size_t ws_size,
                              hipStream_t stream) {
    const float* inputs = (const float*)d_in[0];
    const float* Win    = (const float*)d_in[1];
    const float* Wrec   = (const float*)d_in[2];
    const float* bias   = (const float*)d_in[3];
    const float* resp   = (const float*)d_in[4];
    const float* hasin  = (const float*)d_in[5];
    const int*   np     = (const int*)d_in[6];
    float*       out    = (float*)d_out;

    const int total = in_sizes[0] / NIN;   // H*W pixels

    if (ws_size >= (size_t)PK_BYTES) {
        float* pkbuf = (float*)d_ws;
        pack_kernel<<<1, 128, 0, stream>>>(Win, Wrec, bias, resp, hasin, pkbuf);
        constexpr int P = 2;
        const int block = 256;
        const int grid  = (total + block * P - 1) / (block * P);
        rnn_fused<P><<<grid, block, 0, stream>>>(inputs, pkbuf, Wrec, np, out, total);
    } else {
        const int block = 256;
        const int grid  = (total + block - 1) / block;
        rnn_general<<<grid, block, 0, stream>>>(inputs, Win, Wrec, bias, resp,
                                                hasin, np, out, total);
    }
}

// Round 11
// 103.583 us; speedup vs baseline: 1.0196x; 1.0196x over previous
//
#include <hip/hip_runtime.h>

#define NN   67   // N_OUT + N_HID
#define NOUT 3
#define NIN  4
#define PKW  16                      // floats per neuron in packed blob (64B aligned)
#define PK_FLOATS (NN * PKW)
#define PK_BYTES  (PK_FLOATS * 4)
#define C2   2.885390081777927f      // 2*log2(e)

typedef float v2f __attribute__((ext_vector_type(2)));

__device__ __forceinline__ v2f vfma(v2f a, v2f b, v2f c) {
    return __builtin_elementwise_fma(a, b, c);
}

// Guaranteed-fast transcendentals: raw gfx950 instructions via inline asm.
// (VALU->VALU deps are HW-interlocked on gfx9-lineage; no manual waits needed.)
__device__ __forceinline__ float fexp2(float x) {
    float r; asm("v_exp_f32 %0, %1" : "=v"(r) : "v"(x)); return r;
}
__device__ __forceinline__ float frcp(float x) {
    float r; asm("v_rcp_f32 %0, %1" : "=v"(r) : "v"(x)); return r;
}

// tanh(y) with arg = 2*log2(e)*y pre-applied: tanh = 1 - 2*rcp(exp2(arg)+1)
__device__ __forceinline__ float tanh_sc(float arg) {
    float e = fexp2(arg);
    float r = frcp(e + 1.0f);
    return __builtin_fmaf(-2.0f, r, 1.0f);
}

// Pack per-neuron data: {Win[0..3][j], resp2, bias2, Wrec[j][0..2], pad×7}
// resp2 = hasin*resp*C2, bias2 = hasin*bias*C2  (hasin ∈ {0,1}: h*tanh(y)=tanh(h*y))
__global__ void pack_kernel(const float* __restrict__ Win,
                            const float* __restrict__ Wrec,
                            const float* __restrict__ bias,
                            const float* __restrict__ resp,
                            const float* __restrict__ hasin,
                            float* __restrict__ pk)
{
    int j = threadIdx.x;
    if (j < NN) {
        float h = hasin[j];
        float* p = pk + j * PKW;
        p[0] = Win[0*NN + j]; p[1] = Win[1*NN + j];
        p[2] = Win[2*NN + j]; p[3] = Win[3*NN + j];
        p[4] = resp[j] * h * C2;
        p[5] = bias[j] * h * C2;
        p[6] = Wrec[j*NN + 0]; p[7] = Wrec[j*NN + 1]; p[8] = Wrec[j*NN + 2];
        p[9]=p[10]=p[11]=p[12]=p[13]=p[14]=p[15] = 0.f;
    }
}

// P pixels per thread, processed as P/2 packed float2 chains (v_pk_fma_f32
// eligible). More independent chains per wave = latency hiding via ILP.
template<int P>
__global__ __launch_bounds__(256)
void rnn_fused(const float* __restrict__ inputs,
               const float* __restrict__ pk,
               const float* __restrict__ Wrec,
               const int*   __restrict__ np_ptr,
               float*       __restrict__ out,
               int total)
{
    static_assert(P % 2 == 0, "P must be even");
    constexpr int NC = P / 2;   // packed chains

    __shared__ __align__(16) float spk[PK_FLOATS];
    {
        float4*       d = reinterpret_cast<float4*>(spk);
        const float4* s = reinterpret_cast<const float4*>(pk);
        #pragma unroll
        for (int t = 0; t < (PK_FLOATS/4 + 255) / 256; ++t) {
            int i = threadIdx.x + t * 256;
            if (i < PK_FLOATS / 4) d[i] = s[i];
        }
    }
    __syncthreads();

    const int np   = np_ptr[0];                       // uniform
    const int base = blockIdx.x * (256 * P) + threadIdx.x;

    int    pix[P];
    float4 x[P];
#pragma unroll
    for (int p = 0; p < P; ++p) {                     // coalesced 16B loads
        pix[p] = base + p * 256;
        int idx = pix[p] < total ? pix[p] : total - 1;
        x[p] = reinterpret_cast<const float4*>(inputs)[idx];
    }

    float res[P][NOUT];

    if (np == 2) {
        // transpose inputs into per-feature packed pairs: xf[f][c] = {x[2c].f, x[2c+1].f}
        v2f xf[NIN][NC];
#pragma unroll
        for (int c = 0; c < NC; ++c) {
            xf[0][c] = v2f{x[2*c].x, x[2*c+1].x};
            xf[1][c] = v2f{x[2*c].y, x[2*c+1].y};
            xf[2][c] = v2f{x[2*c].z, x[2*c+1].z};
            xf[3][c] = v2f{x[2*c].w, x[2*c+1].w};
        }

        // acc[o][c] starts as final-pass x@Win[:,o] term
        v2f acc[NOUT][NC];
#pragma unroll
        for (int o = 0; o < NOUT; ++o) {
            const float* q = &spk[o * PKW];
            const v2f w0 = {q[0], q[0]}, w1 = {q[1], q[1]},
                      w2 = {q[2], q[2]}, w3 = {q[3], q[3]};
#pragma unroll
            for (int c = 0; c < NC; ++c) {
                v2f a = xf[0][c] * w0;
                a = vfma(xf[1][c], w1, a);
                a = vfma(xf[2][c], w2, a);
                a = vfma(xf[3][c], w3, a);
                acc[o][c] = a;
            }
        }

        // ---- fused pass0 -> final: a_j dies immediately after 3 acc FMAs ----
#pragma unroll
        for (int j = 0; j < NN; ++j) {
            const float* q = &spk[j * PKW];
            const float4 qa = *reinterpret_cast<const float4*>(q);     // w0..w3
            const float4 qb = *reinterpret_cast<const float4*>(q + 4); // r2,b2,wr0,wr1
            const float  wr2s = q[8];
            const v2f w0  = {qa.x, qa.x}, w1 = {qa.y, qa.y},
                      w2  = {qa.z, qa.z}, w3 = {qa.w, qa.w};
            const v2f r2  = {qb.x, qb.x}, b2 = {qb.y, qb.y};
            const v2f wr0 = {qb.z, qb.z}, wr1 = {qb.w, qb.w}, wr2 = {wr2s, wr2s};
#pragma unroll
            for (int c = 0; c < NC; ++c) {
                v2f agg = xf[0][c] * w0;
                agg = vfma(xf[1][c], w1, agg);
                agg = vfma(xf[2][c], w2, agg);
                agg = vfma(xf[3][c], w3, agg);
                v2f arg = vfma(r2, agg, b2);
                v2f a = v2f{tanh_sc(arg.x), tanh_sc(arg.y)};
                acc[0][c] = vfma(a, wr0, acc[0][c]);
                acc[1][c] = vfma(a, wr1, acc[1][c]);
                acc[2][c] = vfma(a, wr2, acc[2][c]);
            }
        }

        // epilogue: final tanh per output column
#pragma unroll
        for (int o = 0; o < NOUT; ++o) {
            const float* q = &spk[o * PKW];
            const float r2s = q[4], b2s = q[5];
#pragma unroll
            for (int c = 0; c < NC; ++c) {
                res[2*c  ][o] = tanh_sc(__builtin_fmaf(r2s, acc[o][c].x, b2s));
                res[2*c+1][o] = tanh_sc(__builtin_fmaf(r2s, acc[o][c].y, b2s));
            }
        }
    } else if (np <= 0) {
#pragma unroll
        for (int p = 0; p < P; ++p)
#pragma unroll
            for (int o = 0; o < NOUT; ++o) res[p][o] = 0.f;
    } else if (np == 1) {
#pragma unroll
        for (int p = 0; p < P; ++p)
#pragma unroll
            for (int o = 0; o < NOUT; ++o) {
                const float* q = &spk[o * PKW];
                float agg = x[p].x * q[0];
                agg = __builtin_fmaf(x[p].y, q[1], agg);
                agg = __builtin_fmaf(x[p].z, q[2], agg);
                agg = __builtin_fmaf(x[p].w, q[3], agg);
                res[p][o] = tanh_sc(__builtin_fmaf(q[4], agg, q[5]));
            }
    } else {
        // ---- COLD general path (np >= 3): unroll-1 + runtime indexing so
        // its arrays live in scratch and don't inflate hot-path registers ----
#pragma unroll
        for (int p = 0; p < P; ++p) {
            float act[NN];
            #pragma unroll 1
            for (int j = 0; j < NN; ++j) {
                const float* q = &spk[j * PKW];
                float agg = x[p].x * q[0];
                agg = __builtin_fmaf(x[p].y, q[1], agg);
                agg = __builtin_fmaf(x[p].z, q[2], agg);
                agg = __builtin_fmaf(x[p].w, q[3], agg);
                act[j] = tanh_sc(__builtin_fmaf(q[4], agg, q[5]));
            }
            #pragma unroll 1
            for (int t = 1; t < np - 1; ++t) {
                float na[NN];
                #pragma unroll 1
                for (int j = 0; j < NN; ++j) {
                    const float* q = &spk[j * PKW];
                    float agg = x[p].x * q[0];
                    agg = __builtin_fmaf(x[p].y, q[1], agg);
                    agg = __builtin_fmaf(x[p].z, q[2], agg);
                    agg = __builtin_fmaf(x[p].w, q[3], agg);
                    #pragma unroll 1
                    for (int k = 0; k < NN; ++k)
                        agg = __builtin_fmaf(act[k], Wrec[k*NN + j], agg);
                    na[j] = tanh_sc(__builtin_fmaf(q[4], agg, q[5]));
                }
                #pragma unroll 1
                for (int j = 0; j < NN; ++j) act[j] = na[j];
            }
            #pragma unroll
            for (int o = 0; o < NOUT; ++o) {
                const float* q = &spk[o * PKW];
                float agg = x[p].x * q[0];
                agg = __builtin_fmaf(x[p].y, q[1], agg);
                agg = __builtin_fmaf(x[p].z, q[2], agg);
                agg = __builtin_fmaf(x[p].w, q[3], agg);
                #pragma unroll 1
                for (int k = 0; k < NN; ++k)
                    agg = __builtin_fmaf(act[k], Wrec[k*NN + o], agg);
                res[p][o] = tanh_sc(__builtin_fmaf(q[4], agg, q[5]));
            }
        }
    }

#pragma unroll
    for (int p = 0; p < P; ++p)
        if (pix[p] < total) {
            out[pix[p]*NOUT + 0] = res[p][0];
            out[pix[p]*NOUT + 1] = res[p][1];
            out[pix[p]*NOUT + 2] = res[p][2];
        }
}

// ---------- fallback (ws too small): self-contained, any np ----------
__global__ __launch_bounds__(256)
void rnn_general(const float* __restrict__ inputs,
                 const float* __restrict__ Win,
                 const float* __restrict__ Wrec,
                 const float* __restrict__ bias,
                 const float* __restrict__ resp,
                 const float* __restrict__ hasin,
                 const int*   __restrict__ np_ptr,
                 float*       __restrict__ out, int total)
{
    int pix = blockIdx.x * blockDim.x + threadIdx.x;
    if (pix >= total) return;
    const int np = np_ptr[0];
    const float4 x = reinterpret_cast<const float4*>(inputs)[pix];
    float act[NN];
    #pragma unroll 1
    for (int j = 0; j < NN; ++j) act[j] = 0.f;
    #pragma unroll 1
    for (int t = 0; t < np; ++t) {
        float na[NN];
        #pragma unroll 1
        for (int j = 0; j < NN; ++j) {
            float agg = x.x * Win[0*NN+j];
            agg = __builtin_fmaf(x.y, Win[1*NN+j], agg);
            agg = __builtin_fmaf(x.z, Win[2*NN+j], agg);
            agg = __builtin_fmaf(x.w, Win[3*NN+j], agg);
            #pragma unroll 1
            for (int k = 0; k < NN; ++k)
                agg = __builtin_fmaf(act[k], Wrec[k*NN + j], agg);
            na[j] = hasin[j] * tanh_sc(C2 * __builtin_fmaf(resp[j], agg, bias[j]));
        }
        #pragma unroll 1
        for (int j = 0; j < NN; ++j) act[j] = na[j];
    }
    out[pix*NOUT+0] = act[0]; out[pix*NOUT+1] = act[1]; out[pix*NOUT+2] = act[2];
}

extern "C" void kernel_launch(void* const* d_in, const int* in_sizes, int n_in,
                              void* d_out, int out_size, void* d_ws, size_t ws_size,
                              hipStream_t stream) {
    const float* inputs = (const float*)d_in[0];
    const float* Win    = (const float*)d_in[1];
    const float* Wrec   = (const float*)d_in[2];
    const float* bias   = (const float*)d_in[3];
    const float* resp   = (const float*)d_in[4];
    const float* hasin  = (const float*)d_in[5];
    const int*   np     = (const int*)d_in[6];
    float*       out    = (float*)d_out;

    const int total = in_sizes[0] / NIN;   // H*W pixels

    if (ws_size >= (size_t)PK_BYTES) {
        float* pkbuf = (float*)d_ws;
        pack_kernel<<<1, 128, 0, stream>>>(Win, Wrec, bias, resp, hasin, pkbuf);
        constexpr int P = 4;
        const int block = 256;
        const int grid  = (total + block * P - 1) / (block * P);
        rnn_fused<P><<<grid, block, 0, stream>>>(inputs, pkbuf, Wrec, np, out, total);
    } else {
        const int block = 256;
        const int grid  = (total + block - 1) / block;
        rnn_general<<<grid, block, 0, stream>>>(inputs, Win, Wrec, bias, resp,
                                                hasin, np, out, total);
    }
}

// Round 14
// 100.223 us; speedup vs baseline: 1.0538x; 1.0335x over previous
//
#include <hip/hip_runtime.h>

#define NN    67      // N_OUT + N_HID
#define NPAD  68      // padded with one inert zero row -> unroll-4 divides
#define NOUT  3
#define NIN   4
#define PKW8  8       // floats per neuron row: {w'0..3, b2, wr'0..2}
#define PK_FLOATS (NPAD * PKW8)
#define PK_BYTES  (PK_FLOATS * 4)
#define C2 2.885390081777927f   // 2*log2(e)

typedef float v2f __attribute__((ext_vector_type(2)));

__device__ __forceinline__ v2f vfma(v2f a, v2f b, v2f c) {
    return __builtin_elementwise_fma(a, b, c);
}
__device__ __forceinline__ float fexp2(float x) {
    float r; asm("v_exp_f32 %0, %1" : "=v"(r) : "v"(x)); return r;
}
__device__ __forceinline__ float frcp(float x) {
    float r; asm("v_rcp_f32 %0, %1" : "=v"(r) : "v"(x)); return r;
}
// tanh(y) with arg = 2*log2(e)*y pre-applied: tanh = 1 - 2*rcp(exp2(arg)+1)
__device__ __forceinline__ float tanh_sc(float arg) {
    float e = fexp2(arg);
    float r = frcp(e + 1.0f);
    return __builtin_fmaf(-2.0f, r, 1.0f);
}

// Row j: {w'_f = r2_j*Win[f][j] (f<4), b2_j, wr'_c = r2_c*Wrec[j][c] (c<3)}
// r2_j = hasin_j*resp_j*C2, b2_j = hasin_j*bias_j*C2.
// h in {0,1}: h*tanh(y) = tanh(h*y); zero rows j>=NN are inert.
__global__ void pack_kernel(const float* __restrict__ Win,
                            const float* __restrict__ Wrec,
                            const float* __restrict__ bias,
                            const float* __restrict__ resp,
                            const float* __restrict__ hasin,
                            float* __restrict__ pk)
{
    int j = threadIdx.x;
    if (j < NPAD) {
        float* p = pk + j * PKW8;
        if (j < NN) {
            float h  = hasin[j];
            float r2 = resp[j] * h * C2;
            p[0] = Win[0*NN + j] * r2;
            p[1] = Win[1*NN + j] * r2;
            p[2] = Win[2*NN + j] * r2;
            p[3] = Win[3*NN + j] * r2;
            p[4] = bias[j] * h * C2;
            float r20 = resp[0] * hasin[0] * C2;
            float r21 = resp[1] * hasin[1] * C2;
            float r22 = resp[2] * hasin[2] * C2;
            p[5] = Wrec[j*NN + 0] * r20;
            p[6] = Wrec[j*NN + 1] * r21;
            p[7] = Wrec[j*NN + 2] * r22;
        } else {
            p[0]=p[1]=p[2]=p[3]=p[4]=p[5]=p[6]=p[7] = 0.f;
        }
    }
}

template<int P>   // P = 2: one packed v2f chain, 2048 blocks -> 32 waves/CU cap
__global__ __launch_bounds__(256)
void rnn_fused(const float* __restrict__ inputs,
               const float* __restrict__ pk,
               const float* __restrict__ Win,
               const float* __restrict__ Wrec,
               const float* __restrict__ bias,
               const float* __restrict__ resp,
               const float* __restrict__ hasin,
               const int*   __restrict__ np_ptr,
               float*       __restrict__ out,
               int total)
{
    static_assert(P == 2, "this variant is tuned for P=2");

    __shared__ __align__(16) float spk[PK_FLOATS];   // 2176 B
    {
        float4*       d = reinterpret_cast<float4*>(spk);
        const float4* s = reinterpret_cast<const float4*>(pk);
        int i = threadIdx.x;
        if (i < PK_FLOATS / 4) d[i] = s[i];          // 136 float4 < 256 threads
    }
    __syncthreads();

    const int np   = np_ptr[0];                      // uniform
    const int base = blockIdx.x * (256 * P) + threadIdx.x;

    int    pix[P];
    float4 x[P];
#pragma unroll
    for (int p = 0; p < P; ++p) {                    // coalesced 16B loads
        pix[p] = base + p * 256;
        int idx = pix[p] < total ? pix[p] : total - 1;
        x[p] = reinterpret_cast<const float4*>(inputs)[idx];
    }

    float res[P][NOUT];

    if (np == 1 || np == 2) {
        // packed per-feature pairs across the two pixels
        const v2f xf0 = {x[0].x, x[1].x}, xf1 = {x[0].y, x[1].y},
                  xf2 = {x[0].z, x[1].z}, xf3 = {x[0].w, x[1].w};

        // prologue: acc_o = b2_o + x . w'_o   (rows o = 0..2)
        v2f acc[NOUT];
#pragma unroll
        for (int o = 0; o < NOUT; ++o) {
            const float4 qa = *reinterpret_cast<const float4*>(&spk[o * PKW8]);
            const float  b2 = spk[o * PKW8 + 4];
            v2f a = {b2, b2};
            a = vfma(xf0, (v2f){qa.x, qa.x}, a);
            a = vfma(xf1, (v2f){qa.y, qa.y}, a);
            a = vfma(xf2, (v2f){qa.z, qa.z}, a);
            a = vfma(xf3, (v2f){qa.w, qa.w}, a);
            acc[o] = a;
        }

        if (np == 2) {
            // fused pass0 -> final with depth-1 weight prefetch (SSA rotation)
            float4 qa = *reinterpret_cast<const float4*>(&spk[0]);     // j=0 w'
            float4 qb = *reinterpret_cast<const float4*>(&spk[4]);     // j=0 {b2,wr'}
#pragma unroll 4
            for (int j = 0; j < NPAD; ++j) {
                const int jn = (j + 1 < NPAD) ? j + 1 : NPAD - 1;      // branchless
                const float4 qa_n = *reinterpret_cast<const float4*>(&spk[jn * PKW8]);
                const float4 qb_n = *reinterpret_cast<const float4*>(&spk[jn * PKW8 + 4]);

                v2f arg = {qb.x, qb.x};                                 // b2 init
                arg = vfma(xf0, (v2f){qa.x, qa.x}, arg);
                arg = vfma(xf1, (v2f){qa.y, qa.y}, arg);
                arg = vfma(xf2, (v2f){qa.z, qa.z}, arg);
                arg = vfma(xf3, (v2f){qa.w, qa.w}, arg);
                const v2f a = {tanh_sc(arg.x), tanh_sc(arg.y)};
                acc[0] = vfma(a, (v2f){qb.y, qb.y}, acc[0]);
                acc[1] = vfma(a, (v2f){qb.z, qb.z}, acc[1]);
                acc[2] = vfma(a, (v2f){qb.w, qb.w}, acc[2]);

                qa = qa_n; qb = qb_n;
            }
        }
        // epilogue: wr' carries r2_c, acc already includes b2_c -> direct tanh
#pragma unroll
        for (int o = 0; o < NOUT; ++o) {
            res[0][o] = tanh_sc(acc[o].x);
            res[1][o] = tanh_sc(acc[o].y);
        }
    } else if (np <= 0) {
#pragma unroll
        for (int p = 0; p < P; ++p)
#pragma unroll
            for (int o = 0; o < NOUT; ++o) res[p][o] = 0.f;
    } else {
        // ---- COLD general path (np >= 3): reads raw globals; unroll-1 so its
        // scratch arrays don't inflate hot-path registers ----
#pragma unroll
        for (int p = 0; p < P; ++p) {
            float act[NN];
            #pragma unroll 1
            for (int j = 0; j < NN; ++j) {
                float agg = x[p].x * Win[0*NN+j];
                agg = __builtin_fmaf(x[p].y, Win[1*NN+j], agg);
                agg = __builtin_fmaf(x[p].z, Win[2*NN+j], agg);
                agg = __builtin_fmaf(x[p].w, Win[3*NN+j], agg);
                act[j] = hasin[j] * tanh_sc(C2 * __builtin_fmaf(resp[j], agg, bias[j]));
            }
            #pragma unroll 1
            for (int t = 1; t < np - 1; ++t) {
                float na[NN];
                #pragma unroll 1
                for (int j = 0; j < NN; ++j) {
                    float agg = x[p].x * Win[0*NN+j];
                    agg = __builtin_fmaf(x[p].y, Win[1*NN+j], agg);
                    agg = __builtin_fmaf(x[p].z, Win[2*NN+j], agg);
                    agg = __builtin_fmaf(x[p].w, Win[3*NN+j], agg);
                    #pragma unroll 1
                    for (int k = 0; k < NN; ++k)
                        agg = __builtin_fmaf(act[k], Wrec[k*NN + j], agg);
                    na[j] = hasin[j] * tanh_sc(C2 * __builtin_fmaf(resp[j], agg, bias[j]));
                }
                #pragma unroll 1
                for (int j = 0; j < NN; ++j) act[j] = na[j];
            }
            #pragma unroll
            for (int o = 0; o < NOUT; ++o) {
                float agg = x[p].x * Win[0*NN+o];
                agg = __builtin_fmaf(x[p].y, Win[1*NN+o], agg);
                agg = __builtin_fmaf(x[p].z, Win[2*NN+o], agg);
                agg = __builtin_fmaf(x[p].w, Win[3*NN+o], agg);
                #pragma unroll 1
                for (int k = 0; k < NN; ++k)
                    agg = __builtin_fmaf(act[k], Wrec[k*NN + o], agg);
                res[p][o] = hasin[o] * tanh_sc(C2 * __builtin_fmaf(resp[o], agg, bias[o]));
            }
        }
    }

#pragma unroll
    for (int p = 0; p < P; ++p)
        if (pix[p] < total) {
            out[pix[p]*NOUT + 0] = res[p][0];
            out[pix[p]*NOUT + 1] = res[p][1];
            out[pix[p]*NOUT + 2] = res[p][2];
        }
}

// ---------- fallback (ws too small): self-contained, any np ----------
__global__ __launch_bounds__(256)
void rnn_general(const float* __restrict__ inputs,
                 const float* __restrict__ Win,
                 const float* __restrict__ Wrec,
                 const float* __restrict__ bias,
                 const float* __restrict__ resp,
                 const float* __restrict__ hasin,
                 const int*   __restrict__ np_ptr,
                 float*       __restrict__ out, int total)
{
    int pix = blockIdx.x * blockDim.x + threadIdx.x;
    if (pix >= total) return;
    const int np = np_ptr[0];
    const float4 x = reinterpret_cast<const float4*>(inputs)[pix];
    float act[NN];
    #pragma unroll 1
    for (int j = 0; j < NN; ++j) act[j] = 0.f;
    #pragma unroll 1
    for (int t = 0; t < np; ++t) {
        float na[NN];
        #pragma unroll 1
        for (int j = 0; j < NN; ++j) {
            float agg = x.x * Win[0*NN+j];
            agg = __builtin_fmaf(x.y, Win[1*NN+j], agg);
            agg = __builtin_fmaf(x.z, Win[2*NN+j], agg);
            agg = __builtin_fmaf(x.w, Win[3*NN+j], agg);
            #pragma unroll 1
            for (int k = 0; k < NN; ++k)
                agg = __builtin_fmaf(act[k], Wrec[k*NN + j], agg);
            na[j] = hasin[j] * tanh_sc(C2 * __builtin_fmaf(resp[j], agg, bias[j]));
        }
        #pragma unroll 1
        for (int j = 0; j < NN; ++j) act[j] = na[j];
    }
    out[pix*NOUT+0] = act[0]; out[pix*NOUT+1] = act[1]; out[pix*NOUT+2] = act[2];
}

extern "C" void kernel_launch(void* const* d_in, const int* in_sizes, int n_in,
                              void* d_out, int out_size, void* d_ws, size_t ws_size,
                              hipStream_t stream) {
    const float* inputs = (const float*)d_in[0];
    const float* Win    = (const float*)d_in[1];
    const float* Wrec   = (const float*)d_in[2];
    const float* bias   = (const float*)d_in[3];
    const float* resp   = (const float*)d_in[4];
    const float* hasin  = (const float*)d_in[5];
    const int*   np     = (const int*)d_in[6];
    float*       out    = (float*)d_out;

    const int total = in_sizes[0] / NIN;   // H*W pixels

    if (ws_size >= (size_t)PK_BYTES) {
        float* pkbuf = (float*)d_ws;
        pack_kernel<<<1, 128, 0, stream>>>(Win, Wrec, bias, resp, hasin, pkbuf);
        constexpr int P = 2;
        const int block = 256;
        const int grid  = (total + block * P - 1) / (block * P);
        rnn_fused<P><<<grid, block, 0, stream>>>(inputs, pkbuf, Win, Wrec, bias,
                                                 resp, hasin, np, out, total);
    } else {
        const int block = 256;
        const int grid  = (total + block - 1) / block;
        rnn_general<<<grid, block, 0, stream>>>(inputs, Win, Wrec, bias, resp,
                                                hasin, np, out, total);
    }
}